// Round 9
// baseline (2932.100 us; speedup 1.0000x reference)
//
#include <hip/hip_runtime.h>
#include <stdint.h>

#define S_LEN 2048
#define BATCH 32
#define DEMB  512
#define DRNN  256
#define G3    768   // 3*DRNN

typedef __bf16    bf16x8 __attribute__((ext_vector_type(8)));
typedef float     f32x4  __attribute__((ext_vector_type(4)));
typedef _Float16  f16x2  __attribute__((ext_vector_type(2)));
typedef _Float16  f16x8  __attribute__((ext_vector_type(8)));

__device__ __forceinline__ unsigned short f2b(float f) {    // f32 -> bf16 RNE
    unsigned int u = __builtin_bit_cast(unsigned int, f);
    unsigned int r = (u + 0x7fffu + ((u >> 16) & 1u)) >> 16;
    return (unsigned short)r;
}
__device__ __forceinline__ float sigm(float x) {
    float e = __builtin_amdgcn_exp2f(-1.4426950408889634f * x);
    return __builtin_amdgcn_rcpf(1.0f + e);
}
__device__ __forceinline__ float tanh_f(float x) {
    float e = __builtin_amdgcn_exp2f(2.8853900817779268f * x);  // e^(2x)
    return 1.0f - 2.0f * __builtin_amdgcn_rcpf(e + 1.0f);       // safe at +-inf
}
__device__ __forceinline__ float dot2acc(f16x2 w, f16x2 h, float acc) {
    return __builtin_amdgcn_fdot2(w, h, acc, false);
}
__device__ __forceinline__ f16x2 pk_f16(float lo, float hi) {
    return __builtin_bit_cast(f16x2, __builtin_amdgcn_cvt_pkrtz(lo, hi));
}
// DPP row-rotate move (within 16-lane row), VALU pipe.
template <int CTRL>
__device__ __forceinline__ float dpp_rot(float x) {
    return __builtin_bit_cast(float, __builtin_amdgcn_update_dpp(
        0, __builtin_bit_cast(int, x), CTRL, 0xF, 0xF, true));
}
__device__ __forceinline__ float rred(float a) {   // all-reduce over 8 lanes
    a += dpp_rot<0x122>(a);    // row_ror:2   (stride-2 parity group)
    a += dpp_rot<0x124>(a);    // row_ror:4
    a += dpp_rot<0x128>(a);    // row_ror:8
    return a;
}

// ---------------- Kernel A: gi = x @ w_ih^T + bias  (both dirs, one chunk) --
// bias = b_ih[g] + (g<512 ? b_hh[g] : 0): r/z-gate b_hh folded here (they sit
// outside the r-multiply); n-gate b_hh stays in the recurrence (inside r*(.)).
__global__ __launch_bounds__(256) void gi_gemm(
    const float* __restrict__ x,
    const float* __restrict__ wih_f,
    const float* __restrict__ bih_f,
    const float* __restrict__ bhh_f,
    const float* __restrict__ wih_b,
    const float* __restrict__ bih_b,
    const float* __restrict__ bhh_b,
    float* __restrict__ gi,
    int p0, int chunkM)
{
    const int dir = blockIdx.z;
    const float* wih = dir ? wih_b : wih_f;
    const float* bih = dir ? bih_b : bih_f;
    const float* bhh = dir ? bhh_b : bhh_f;
    float* giD = gi + (size_t)dir * (size_t)chunkM * G3;

    __shared__ __align__(16) unsigned short sA[128 * 32];
    __shared__ __align__(16) unsigned short sB[128 * 32];

    const int tid  = threadIdx.x;
    const int lane = tid & 63, wv = tid >> 6;
    const int wr = wv >> 1, wc = wv & 1;        // wave quadrant (2x2 of 64x64)
    const int lr = lane & 15, kq = lane >> 4;

    const int m0 = blockIdx.x * 128;
    const int n0 = blockIdx.y * 128;

    f32x4 acc[4][4];
    #pragma unroll
    for (int i = 0; i < 4; ++i)
        #pragma unroll
        for (int j = 0; j < 4; ++j) acc[i][j] = (f32x4){0.f, 0.f, 0.f, 0.f};

    const int srow = tid >> 3;            // 32 rows per pass, 8 threads/row
    const int scol = (tid & 7) * 4;       // 4 floats per thread

    for (int ks = 0; ks < 16; ++ks) {
        const int k0 = ks * 32;
        #pragma unroll
        for (int r = 0; r < 4; ++r) {
            const int row = srow + r * 32;
            {
                const int m = m0 + row;
                const int p = p0 + (m >> 5), b = m & 31;
                const int t = dir ? (S_LEN - 1 - p) : p;
                const float4 v = *(const float4*)&x[((size_t)t * BATCH + b) * DEMB + k0 + scol];
                ushort4 h4; h4.x = f2b(v.x); h4.y = f2b(v.y); h4.z = f2b(v.z); h4.w = f2b(v.w);
                *(ushort4*)&sA[row * 32 + scol] = h4;
            }
            {
                const float4 v = *(const float4*)&wih[(size_t)(n0 + row) * DEMB + k0 + scol];
                ushort4 h4; h4.x = f2b(v.x); h4.y = f2b(v.y); h4.z = f2b(v.z); h4.w = f2b(v.w);
                *(ushort4*)&sB[row * 32 + scol] = h4;
            }
        }
        __syncthreads();
        bf16x8 af[4], bfr[4];
        #pragma unroll
        for (int i = 0; i < 4; ++i) {
            af[i]  = *(const bf16x8*)&sA[(wr * 64 + i * 16 + lr) * 32 + kq * 8];
            bfr[i] = *(const bf16x8*)&sB[(wc * 64 + i * 16 + lr) * 32 + kq * 8];
        }
        #pragma unroll
        for (int i = 0; i < 4; ++i)
            #pragma unroll
            for (int j = 0; j < 4; ++j)
                acc[i][j] = __builtin_amdgcn_mfma_f32_16x16x32_bf16(
                    af[i], bfr[j], acc[i][j], 0, 0, 0);
        __syncthreads();
    }
    #pragma unroll
    for (int j = 0; j < 4; ++j) {
        const int g = n0 + wc * 64 + j * 16 + lr;
        const float bias = bih[g] + (g < 512 ? bhh[g] : 0.0f);
        #pragma unroll
        for (int i = 0; i < 4; ++i) {
            const int mbase = m0 + wr * 64 + i * 16 + kq * 4;
            #pragma unroll
            for (int r2 = 0; r2 < 4; ++r2)
                giD[(size_t)(mbase + r2) * G3 + g] = acc[i][j][r2] + bias;
        }
    }
}

// ---------------- Kernel B: the recurrence (one chunk) ----------------------
// 64 WGs (one (b,dir) chain), 1024 threads, 16 waves, 4 waves/SIMD.
// Lane l: c=l&15, row=l>>4, p=c&1, ke=c>>1 (k-eighth). jp = w*8+row*2+p,
// thread owns js {2jp, 2jp+1} x k-eighth [ke*32, ke*32+32).
// Weights: 2js x 3g x 32 f16 = 96 VGPRs -> total pressure ~128, no AGPR park.
// k-reduce: VALU DPP row_ror 2/4/8 over the stride-2 parity group (no LDS).
// h: f16 in LDS, pad-swizzled addr=2k+(k>>5)*16 -> 8 ke-groups on disjoint
// bank quads, 4 ds_read_b128/thread/step. Double-buffered, 1 barrier/step.
// Gates: lane-select (lo-lanes j0, hi-lanes j1), ror:8 swap recovers pair.
__global__ __launch_bounds__(1024)
__attribute__((amdgpu_waves_per_eu(4, 4)))
void gru_rec(
    const float* __restrict__ gi,               // [2][chunk*32][768]
    const float* __restrict__ whh_f,
    const float* __restrict__ bhh_f,
    const float* __restrict__ whh_b,
    const float* __restrict__ bhh_b,
    float* __restrict__ out,                    // [S*B*512] ++ [2*B*256]
    float* __restrict__ hcarry,                 // [2*B*256]
    int p0, int chunk)
{
    const int wg  = blockIdx.x;
    const int b   = wg & 31, dir = wg >> 5;
    const float* whh = dir ? whh_b : whh_f;
    const float* bhh = dir ? bhh_b : bhh_f;
    const float* giD = gi + (size_t)dir * (size_t)(chunk * BATCH) * G3;

    const int tid = threadIdx.x;
    const int w = tid >> 6, l = tid & 63;
    const int c = l & 15, row = l >> 4;
    const int p = c & 1, ke = c >> 1;
    const int jp = w * 8 + row * 2 + p;        // [0,128)
    const int j0 = jp * 2;
    const bool hi = (c & 8) != 0;              // this lane's gate-set: j1

    __shared__ __align__(16) unsigned char hb0[640];
    __shared__ __align__(16) unsigned char hb1[640];

    union u8 { f16x8 v; f16x2 pp[4]; };

    // ---- weights: 24 f16x8 = 96 VGPRs (f32 -> packed f16) ----
    f16x8 wr[6][4];
    #pragma unroll
    for (int g = 0; g < 3; ++g)
        #pragma unroll
        for (int js = 0; js < 2; ++js) {
            const float* s = whh + (size_t)(g * 256 + j0 + js) * DRNN + ke * 32;
            #pragma unroll
            for (int cc = 0; cc < 4; ++cc) {
                float4 lo = *(const float4*)(s + cc * 8);
                float4 hf = *(const float4*)(s + cc * 8 + 4);
                u8 t;
                t.pp[0] = pk_f16(lo.x, lo.y); t.pp[1] = pk_f16(lo.z, lo.w);
                t.pp[2] = pk_f16(hf.x, hf.y); t.pp[3] = pk_f16(hf.z, hf.w);
                wr[g * 2 + js][cc] = t.v;
            }
            __builtin_amdgcn_sched_barrier(0);   // cap load-hoist reg spike
        }

    const float bn = bhh[512 + j0 + (hi ? 1 : 0)];   // n-gate b_hh (not folded)

    float2 hc; hc.x = 0.f; hc.y = 0.f;
    if (p0 != 0) hc = *(const float2*)&hcarry[(dir * BATCH + b) * DRNN + j0];
    float hold = hi ? hc.y : hc.x;

    const int wb = 4 * jp + (jp >> 4) * 16;          // h write byte offset
    if (c < 2)
        *(unsigned int*)(hb0 + wb) =
            __builtin_bit_cast(unsigned int, pk_f16(hc.x, hc.y));
    __syncthreads();

    // gi pointer (float2, j0 even): g-offsets 0 / +1024B / +2048B fold to imm
    const float2* gp = (const float2*)(giD + (size_t)b * G3 + j0);
    float2 pg0 = gp[0], pg1 = gp[128], pg2 = gp[256];
    gp += 12288;                                     // next step (+98304 B)

    const int t0 = dir ? (S_LEN - 1 - p0) : p0;
    float* outp = out + ((size_t)t0 * BATCH + b) * 512 + dir * 256 + j0;
    const int dstep = dir ? -(BATCH * 512) : (BATCH * 512);

    for (int step = 0; step < chunk; ++step) {
        const bool odd = (step & 1) != 0;
        const unsigned char* hv = odd ? hb1 : hb0;   // read buffer
        unsigned char*       hw = odd ? hb0 : hb1;   // write buffer

        // acc init: gi lands once (ke==0 lane) so the k-reduce sums it in.
        const bool k0lane = (ke == 0);
        float a00 = k0lane ? pg0.x : 0.f, a01 = k0lane ? pg0.y : 0.f;  // r gate
        float a10 = k0lane ? pg1.x : 0.f, a11 = k0lane ? pg1.y : 0.f;  // z gate
        float a20 = 0.f,                  a21 = 0.f;                   // n (pure h)
        float2 gin = pg2;                                              // n-gate gi

        if (step + 1 < chunk) { pg0 = gp[0]; pg1 = gp[128]; pg2 = gp[256]; gp += 12288; }

        // ---- dot phase: 4 ds_read_b128 + 96 v_dot2 ----
        #pragma unroll
        for (int cc = 0; cc < 4; ++cc) {
            u8 H; H.v = *(const f16x8*)(hv + ke * 80 + cc * 16);
            u8 W0, W1, W2, W3, W4, W5;
            W0.v = wr[0][cc]; W1.v = wr[1][cc]; W2.v = wr[2][cc];
            W3.v = wr[3][cc]; W4.v = wr[4][cc]; W5.v = wr[5][cc];
            #pragma unroll
            for (int i = 0; i < 4; ++i) {
                a00 = dot2acc(W0.pp[i], H.pp[i], a00);
                a01 = dot2acc(W1.pp[i], H.pp[i], a01);
                a10 = dot2acc(W2.pp[i], H.pp[i], a10);
                a11 = dot2acc(W3.pp[i], H.pp[i], a11);
                a20 = dot2acc(W4.pp[i], H.pp[i], a20);
                a21 = dot2acc(W5.pp[i], H.pp[i], a21);
            }
        }

        // ---- k-reduce on VALU (DPP rotations within the parity group) ----
        a00 = rred(a00); a01 = rred(a01);
        a10 = rred(a10); a11 = rred(a11);
        a20 = rred(a20); a21 = rred(a21);

        // ---- gates: lo-lanes compute j0's set, hi-lanes j1's ----
        float A0 = hi ? a01 : a00;
        float A1 = hi ? a11 : a10;
        float A2 = hi ? a21 : a20;
        float gn = hi ? gin.y : gin.x;
        float r  = sigm(A0);
        float z  = sigm(A1);
        float n  = tanh_f(gn + r * (A2 + bn));
        float hy = n + z * (hold - n);
        hold = hy;
        float hyo = dpp_rot<0x128>(hy);              // partner j's h (ror:8)

        if (c < 2)
            *(unsigned int*)(hw + wb) =
                __builtin_bit_cast(unsigned int, pk_f16(hy, hyo));
        __syncthreads();
        if (c < 2) { float2 o; o.x = hy; o.y = hyo; *(float2*)outp = o; }
        outp += dstep;
    }

    float hfin_o = dpp_rot<0x128>(hold);
    if (c < 2) {
        float2 o; o.x = hold; o.y = hfin_o;
        *(float2*)&hcarry[(dir * BATCH + b) * DRNN + j0] = o;
        if (p0 + chunk == S_LEN)
            *(float2*)&out[(size_t)S_LEN * BATCH * 512 + (dir * BATCH + b) * DRNN + j0] = o;
    }
}

// ---------------------------------------------------------------------------
extern "C" void kernel_launch(void* const* d_in, const int* in_sizes, int n_in,
                              void* d_out, int out_size, void* d_ws, size_t ws_size,
                              hipStream_t stream) {
    const float* x     = (const float*)d_in[0];
    const float* wih_f = (const float*)d_in[1];
    const float* whh_f = (const float*)d_in[2];
    const float* bih_f = (const float*)d_in[3];
    const float* bhh_f = (const float*)d_in[4];
    const float* wih_b = (const float*)d_in[5];
    const float* whh_b = (const float*)d_in[6];
    const float* bih_b = (const float*)d_in[7];
    const float* bhh_b = (const float*)d_in[8];
    float* out = (float*)d_out;

    const size_t carry_bytes = (size_t)2 * BATCH * DRNN * 4;    // 64 KB
    int chunk = 0;
    for (int cs = S_LEN; cs >= 16; cs >>= 1) {
        size_t need = carry_bytes + (size_t)2 * cs * BATCH * G3 * 4;
        if (ws_size >= need) { chunk = cs; break; }
    }
    if (!chunk) return;   // ws too small — visible as unchanged output

    float* hcarry = (float*)d_ws;
    float* gi     = (float*)((char*)d_ws + carry_bytes);
    const int chunkM = chunk * BATCH;

    for (int p0 = 0; p0 < S_LEN; p0 += chunk) {
        gi_gemm<<<dim3(chunkM / 128, 6, 2), 256, 0, stream>>>(
            x, wih_f, bih_f, bhh_f, wih_b, bih_b, bhh_b, gi, p0, chunkM);
        gru_rec<<<dim3(64), 1024, 0, stream>>>(
            gi, whh_f, bhh_f, whh_b, bhh_b, out, hcarry, p0, chunk);
    }
}

// Round 10
// 2757.720 us; speedup vs baseline: 1.0632x; 1.0632x over previous
//
#include <hip/hip_runtime.h>
#include <stdint.h>

#define S_LEN 2048
#define BATCH 32
#define DEMB  512
#define DRNN  256
#define G3    768   // 3*DRNN

typedef __bf16    bf16x8 __attribute__((ext_vector_type(8)));
typedef float     f32x4  __attribute__((ext_vector_type(4)));
typedef _Float16  f16x2  __attribute__((ext_vector_type(2)));
typedef _Float16  f16x8  __attribute__((ext_vector_type(8)));

__device__ __forceinline__ unsigned short f2b(float f) {    // f32 -> bf16 RNE
    unsigned int u = __builtin_bit_cast(unsigned int, f);
    unsigned int r = (u + 0x7fffu + ((u >> 16) & 1u)) >> 16;
    return (unsigned short)r;
}
__device__ __forceinline__ float sigm(float x) {
    float e = __builtin_amdgcn_exp2f(-1.4426950408889634f * x);
    return __builtin_amdgcn_rcpf(1.0f + e);
}
__device__ __forceinline__ float tanh_f(float x) {
    float e = __builtin_amdgcn_exp2f(2.8853900817779268f * x);  // e^(2x)
    return 1.0f - 2.0f * __builtin_amdgcn_rcpf(e + 1.0f);       // safe at +-inf
}
__device__ __forceinline__ float dot2acc(f16x2 w, f16x2 h, float acc) {
    return __builtin_amdgcn_fdot2(w, h, acc, false);
}
__device__ __forceinline__ f16x2 pk_f16(float lo, float hi) {
    return __builtin_bit_cast(f16x2, __builtin_amdgcn_cvt_pkrtz(lo, hi));
}

// ---------------- Kernel A: gi = x @ w_ih^T + b_ih  (both dirs, one chunk) --
__global__ __launch_bounds__(256) void gi_gemm(
    const float* __restrict__ x,
    const float* __restrict__ wih_f,
    const float* __restrict__ bih_f,
    const float* __restrict__ wih_b,
    const float* __restrict__ bih_b,
    float* __restrict__ gi,
    int p0, int chunkM)
{
    const int dir = blockIdx.z;
    const float* wih = dir ? wih_b : wih_f;
    const float* bih = dir ? bih_b : bih_f;
    float* giD = gi + (size_t)dir * (size_t)chunkM * G3;

    __shared__ __align__(16) unsigned short sA[128 * 32];
    __shared__ __align__(16) unsigned short sB[128 * 32];

    const int tid  = threadIdx.x;
    const int lane = tid & 63, wv = tid >> 6;
    const int wr = wv >> 1, wc = wv & 1;        // wave quadrant (2x2 of 64x64)
    const int lr = lane & 15, kq = lane >> 4;

    const int m0 = blockIdx.x * 128;
    const int n0 = blockIdx.y * 128;

    f32x4 acc[4][4];
    #pragma unroll
    for (int i = 0; i < 4; ++i)
        #pragma unroll
        for (int j = 0; j < 4; ++j) acc[i][j] = (f32x4){0.f, 0.f, 0.f, 0.f};

    const int srow = tid >> 3;            // 32 rows per pass, 8 threads/row
    const int scol = (tid & 7) * 4;       // 4 floats per thread

    for (int ks = 0; ks < 16; ++ks) {
        const int k0 = ks * 32;
        #pragma unroll
        for (int r = 0; r < 4; ++r) {
            const int row = srow + r * 32;
            {
                const int m = m0 + row;
                const int p = p0 + (m >> 5), b = m & 31;
                const int t = dir ? (S_LEN - 1 - p) : p;
                const float4 v = *(const float4*)&x[((size_t)t * BATCH + b) * DEMB + k0 + scol];
                ushort4 h4; h4.x = f2b(v.x); h4.y = f2b(v.y); h4.z = f2b(v.z); h4.w = f2b(v.w);
                *(ushort4*)&sA[row * 32 + scol] = h4;
            }
            {
                const float4 v = *(const float4*)&wih[(size_t)(n0 + row) * DEMB + k0 + scol];
                ushort4 h4; h4.x = f2b(v.x); h4.y = f2b(v.y); h4.z = f2b(v.z); h4.w = f2b(v.w);
                *(ushort4*)&sB[row * 32 + scol] = h4;
            }
        }
        __syncthreads();
        bf16x8 af[4], bfr[4];
        #pragma unroll
        for (int i = 0; i < 4; ++i) {
            af[i]  = *(const bf16x8*)&sA[(wr * 64 + i * 16 + lr) * 32 + kq * 8];
            bfr[i] = *(const bf16x8*)&sB[(wc * 64 + i * 16 + lr) * 32 + kq * 8];
        }
        #pragma unroll
        for (int i = 0; i < 4; ++i)
            #pragma unroll
            for (int j = 0; j < 4; ++j)
                acc[i][j] = __builtin_amdgcn_mfma_f32_16x16x32_bf16(
                    af[i], bfr[j], acc[i][j], 0, 0, 0);
        __syncthreads();
    }
    #pragma unroll
    for (int j = 0; j < 4; ++j) {
        const int g = n0 + wc * 64 + j * 16 + lr;
        const float bias = bih[g];
        #pragma unroll
        for (int i = 0; i < 4; ++i) {
            const int mbase = m0 + wr * 64 + i * 16 + kq * 4;
            #pragma unroll
            for (int r2 = 0; r2 < 4; ++r2)
                giD[(size_t)(mbase + r2) * G3 + g] = acc[i][j][r2] + bias;
        }
    }
}

// ---------------- Kernel B: the recurrence (one chunk) ----------------------
// 64 WGs: one (batch, direction) chain each. 512 threads, 8 waves.
// Thread = (wave w, lane l): j = w*32 + (l&31) in [0,256), kh = l>>5 (k-half).
// ALL THREE gate weight slices in arch VGPRs (192 regs as 48 f16x8).
// r3..r9 post-mortems: the register allocator targets the occupancy it
// computes from RESOURCES (tiny LDS -> 2 WG/CU -> 8 waves/SIMD -> 64-VGPR
// budget) and parks the weight arrays in AGPRs, re-reading them through
// v_accvgpr_read every step (~2x VALU on the serial path; VGPR_Count
// 128/128/64/116/128/64 across rounds while requests were 192/96).
// Countermeasure here: a 97 KB static LDS pad caps occupancy at 1 WG/CU
// (8 waves/CU = 2/SIMD) -> 256-VGPR budget -> no reason to demote.
__global__ __launch_bounds__(512)
__attribute__((amdgpu_waves_per_eu(2, 2)))
void gru_rec(
    const float* __restrict__ gi,               // [2][chunk*32][768]
    const float* __restrict__ whh_f,
    const float* __restrict__ bhh_f,
    const float* __restrict__ whh_b,
    const float* __restrict__ bhh_b,
    float* __restrict__ out,                    // [S*B*512] ++ [2*B*256]
    float* __restrict__ hcarry,                 // [2*B*256]
    int p0, int chunk)
{
    const int wg  = blockIdx.x;
    const int b   = wg & 31, dir = wg >> 5;
    const float* whh = dir ? whh_b : whh_f;
    const float* bhh = dir ? bhh_b : bhh_f;
    const float* giD = gi + (size_t)dir * (size_t)(chunk * BATCH) * G3;

    const int tid = threadIdx.x;
    const int j   = ((tid >> 6) << 5) | (tid & 31);   // wave*32 + (lane&31)
    const int kh  = (tid >> 5) & 1;                   // k-half

    __shared__ __align__(16) _Float16 h16[2][DRNN];   // double buffer
    // Occupancy cap: 97 KB static LDS -> exactly 1 WG/CU. Guard write is
    // blockIdx-dependent (never true at runtime, not provable at compile).
    __shared__ __align__(16) unsigned char occ_pad[97 * 1024];
    if ((int)blockIdx.x < 0)
        ((volatile unsigned char*)occ_pad)[tid] = 1;

    union u8 { f16x8 v; f16x2 p[4]; };

    // ---- all 3 gate weight slices into registers (f32 -> packed f16) ----
    f16x8 w[3][16];                                   // 192 VGPRs
    #pragma unroll
    for (int g = 0; g < 3; ++g) {
        const float* s = whh + (size_t)(g * 256 + j) * DRNN + kh * 128;
        #pragma unroll
        for (int c = 0; c < 16; ++c) {
            float4 lo = *(const float4*)(s + c * 8);
            float4 hi = *(const float4*)(s + c * 8 + 4);
            u8 t;
            t.p[0] = pk_f16(lo.x, lo.y); t.p[1] = pk_f16(lo.z, lo.w);
            t.p[2] = pk_f16(hi.x, hi.y); t.p[3] = pk_f16(hi.z, hi.w);
            w[g][c] = t.v;
            if ((c & 3) == 3) __builtin_amdgcn_sched_barrier(0);  // cap hoist spike
        }
    }

    const float bh0 = bhh[j], bh1 = bhh[256 + j], bh2 = bhh[512 + j];
    float hold = (p0 == 0) ? 0.f : hcarry[(dir * BATCH + b) * DRNN + j];
    if (kh == 0) h16[0][j] = (_Float16)hold;
    __syncthreads();

    // prefetch gi for step 0 (kh-redundant, same addr -> broadcast)
    float c0, c1, c2;
    {
        const float* p = giD + (size_t)b * G3;
        c0 = p[j]; c1 = p[256 + j]; c2 = p[512 + j];
    }

    const f16x8* hvA = (const f16x8*)&h16[0][kh * 128];   // read, even steps
    const f16x8* hvB = (const f16x8*)&h16[1][kh * 128];   // read, odd steps

    for (int step = 0; step < chunk; ++step) {
        const int pos = p0 + step;
        const int t = dir ? (S_LEN - 1 - pos) : pos;
        const bool odd = (step & 1) != 0;
        const f16x8* hv = odd ? hvB : hvA;

        // prefetch next step's gi (hidden under the dot phase)
        float n0g = 0.f, n1g = 0.f, n2g = 0.f;
        if (step + 1 < chunk) {
            const float* p = giD + (size_t)((step + 1) * BATCH + b) * G3;
            n0g = p[j]; n1g = p[256 + j]; n2g = p[512 + j];
        }

        // ---- dot phase over this thread's k-half (192 dot2, all from VGPR) --
        float a0 = 0.f, a1 = 0.f, a2 = 0.f;
        #pragma unroll
        for (int cc = 0; cc < 16; ++cc) {
            u8 H, A, B, C;
            H.v = hv[cc];             // uniform addr per half-wave -> broadcast
            A.v = w[0][cc]; B.v = w[1][cc]; C.v = w[2][cc];
            #pragma unroll
            for (int i = 0; i < 4; ++i) {
                a0 = dot2acc(A.p[i], H.p[i], a0);
                a1 = dot2acc(B.p[i], H.p[i], a1);
                a2 = dot2acc(C.p[i], H.p[i], a2);
            }
        }
        // ---- k-half reduce (lanes l and l^32 share the same j) ----
        a0 += __shfl_xor(a0, 32, 64);
        a1 += __shfl_xor(a1, 32, 64);
        a2 += __shfl_xor(a2, 32, 64);

        // ---- gates (all lanes; kh pair computes identically) ----
        float r  = sigm(c0 + a0 + bh0);
        float z  = sigm(c1 + a1 + bh1);
        float n  = tanh_f(c2 + r * (a2 + bh2));
        float hy = n + z * (hold - n);
        hold = hy;
        if (kh == 0) h16[odd ? 0 : 1][j] = (_Float16)hy;  // other buffer, no WAR
        __syncthreads();
        // store AFTER the barrier: gets a whole dot-phase to retire.
        if (kh == 0)
            out[((size_t)t * BATCH + b) * 512 + dir * 256 + j] = hy;
        c0 = n0g; c1 = n1g; c2 = n2g;
    }

    if (kh == 0) {
        hcarry[(dir * BATCH + b) * DRNN + j] = hold;
        if (p0 + chunk == S_LEN)
            out[(size_t)S_LEN * BATCH * 512 + (dir * BATCH + b) * DRNN + j] = hold;
    }
}

// ---------------------------------------------------------------------------
extern "C" void kernel_launch(void* const* d_in, const int* in_sizes, int n_in,
                              void* d_out, int out_size, void* d_ws, size_t ws_size,
                              hipStream_t stream) {
    const float* x     = (const float*)d_in[0];
    const float* wih_f = (const float*)d_in[1];
    const float* whh_f = (const float*)d_in[2];
    const float* bih_f = (const float*)d_in[3];
    const float* bhh_f = (const float*)d_in[4];
    const float* wih_b = (const float*)d_in[5];
    const float* whh_b = (const float*)d_in[6];
    const float* bih_b = (const float*)d_in[7];
    const float* bhh_b = (const float*)d_in[8];
    float* out = (float*)d_out;

    const size_t carry_bytes = (size_t)2 * BATCH * DRNN * 4;    // 64 KB
    int chunk = 0;
    for (int c = S_LEN; c >= 16; c >>= 1) {
        size_t need = carry_bytes + (size_t)2 * c * BATCH * G3 * 4;
        if (ws_size >= need) { chunk = c; break; }
    }
    if (!chunk) return;   // ws too small — visible as unchanged output

    float* hcarry = (float*)d_ws;
    float* gi     = (float*)((char*)d_ws + carry_bytes);
    const int chunkM = chunk * BATCH;

    for (int p0 = 0; p0 < S_LEN; p0 += chunk) {
        gi_gemm<<<dim3(chunkM / 128, 6, 2), 256, 0, stream>>>(
            x, wih_f, bih_f, wih_b, bih_b, gi, p0, chunkM);
        gru_rec<<<dim3(64), 512, 0, stream>>>(
            gi, whh_f, bhh_f, whh_b, bhh_b, out, hcarry, p0, chunk);
    }
}